// Round 1
// baseline (642.925 us; speedup 1.0000x reference)
//
#include <hip/hip_runtime.h>
#include <math.h>

#define B_  32
#define NA_ 32768
#define C_  81
#define NG_ 24

typedef const __attribute__((address_space(1))) unsigned int* gas_ptr;
typedef __attribute__((address_space(3))) unsigned int* las_ptr;

// ---------- helpers ----------
__device__ inline float wave_sum_f(float v) {
  #pragma unroll
  for (int s = 32; s >= 1; s >>= 1) v += __shfl_xor(v, s);
  return v;
}
__device__ inline unsigned long long shflx_u64(unsigned long long v, int s) {
  int lo = __shfl_xor((int)(unsigned)(v & 0xFFFFFFFFULL), s);
  int hi = __shfl_xor((int)(unsigned)(v >> 32), s);
  return ((unsigned long long)(unsigned)hi << 32) | (unsigned)lo;
}

// ---------- K1b: one block per (gt, batch): full argmax over anchors ----------
// Also zeroes the accumulators + out (block (0,0)); plain store, no atomics.
__global__ __launch_bounds__(256) void k_match_b(
    const float* __restrict__ anchors, const float* __restrict__ gt_boxes,
    int* __restrict__ best_anchor,
    int* num_pos_g, int* notneg_g, float* pos_ce_g, float* reg_sum_g, float* out)
{
  const int g = blockIdx.x, b = blockIdx.y;
  const int tid = threadIdx.x, wave = tid >> 6, lane = tid & 63;
  if (g == 0 && b == 0) {
    if (tid < B_) { num_pos_g[tid] = 0; notneg_g[tid] = 0; pos_ce_g[tid] = 0.f; reg_sum_g[tid] = 0.f; }
    else if (tid < B_ + 3) out[tid - B_] = 0.f;
  }
  const float* gp = gt_boxes + ((size_t)b * NG_ + g) * 4;
  const float gx0 = gp[0] - 0.5f * gp[2], gy0 = gp[1] - 0.5f * gp[3];
  const float gx1 = gp[0] + 0.5f * gp[2], gy1 = gp[1] + 0.5f * gp[3];
  const float area_g = (gx1 - gx0) * (gy1 - gy0);
  unsigned long long key = 0ULL;   // (iou_bits<<32) | ~a  : max => first-max anchor
  #pragma unroll 4
  for (int i = 0; i < NA_ / 256; ++i) {
    const int a = i * 256 + tid;                 // increasing a per thread
    const float4 anc = ((const float4*)anchors)[a];
    const float ax0 = anc.x - 0.5f * anc.z, ay0 = anc.y - 0.5f * anc.w;
    const float ax1 = anc.x + 0.5f * anc.z, ay1 = anc.y + 0.5f * anc.w;
    float lx = fmaxf(ax0, gx0), ly = fmaxf(ay0, gy0);
    float rx = fminf(ax1, gx1), ry = fminf(ay1, gy1);
    float ww = fmaxf(rx - lx, 0.f), hh = fmaxf(ry - ly, 0.f);
    float inter = ww * hh;
    float uni = (ax1 - ax0) * (ay1 - ay0) + area_g - inter;
    float iou = inter / fmaxf(uni, 1e-12f);
    unsigned long long k2 =
        ((unsigned long long)__float_as_uint(iou) << 32) | (unsigned)(~(unsigned)a);
    if (k2 > key) key = k2;
  }
  #pragma unroll
  for (int s = 32; s >= 1; s >>= 1) {
    unsigned long long o = shflx_u64(key, s);
    if (o > key) key = o;
  }
  __shared__ unsigned long long red[4];
  if (lane == 0) red[wave] = key;
  __syncthreads();
  if (tid == 0) {
    unsigned long long k = red[0];
    for (int w = 1; w < 4; ++w) if (red[w] > k) k = red[w];
    best_anchor[b * NG_ + g] = (int)(~(unsigned)k);
  }
}

// ---------- K2: fused match_a + CE. 1-wave blocks, 7 blocks/CU (LDS 20.7KB) ----------
// Single-wave block => __syncthreads is a near-free vmcnt(0) drain; 7 independent
// blocks/CU keep HBM loads in flight continuously (no stage->compute convoy).
#define TPB 64   // threads = anchors per block; LDS tile = 64*81*4 = 20736 B
__global__ __launch_bounds__(64) void k_ce(
    const float* __restrict__ cls_pred, const float* __restrict__ box_pred,
    const float* __restrict__ anchors, const float* __restrict__ gt_boxes,
    const int* __restrict__ gt_labels, const int* __restrict__ best_anchor,
    int* __restrict__ neg_bits,
    int* __restrict__ num_pos_g, int* __restrict__ notneg_g,
    float* __restrict__ pos_ce_g, float* __restrict__ reg_sum_g)
{
  __shared__ float tile[TPB * C_];
  __shared__ float4 gt_xyxy[NG_];
  __shared__ float4 gt_cc[NG_];
  __shared__ float  gt_area[NG_];
  __shared__ int    label_sh[NG_];
  __shared__ int    best_a_sh[NG_];
  const int b = blockIdx.y;
  const int tid = threadIdx.x;
  const int a0 = blockIdx.x * TPB;
  const int a = a0 + tid;
  const size_t idx = (size_t)b * NA_ + a;

  // ---- stage small per-batch GT data (lanes < 24) ----
  if (tid < NG_) {
    const float* g = gt_boxes + ((size_t)b * NG_ + tid) * 4;
    const float cx = g[0], cy = g[1], w = g[2], h = g[3];
    const float x0 = cx - 0.5f * w, y0 = cy - 0.5f * h;
    const float x1 = cx + 0.5f * w, y1 = cy + 0.5f * h;
    gt_xyxy[tid] = make_float4(x0, y0, x1, y1);
    gt_cc[tid]   = make_float4(cx, cy, w, h);
    gt_area[tid] = (x1 - x0) * (y1 - y0);
    label_sh[tid]  = gt_labels[b * NG_ + tid];
    best_a_sh[tid] = best_anchor[b * NG_ + tid];
  }

  // ---- stage 64 rows (contiguous 20736 B) global -> LDS, 16B chunks ----
  {
    const unsigned int* gtile =
        (const unsigned int*)(cls_pred + ((size_t)b * NA_ + a0) * C_);
    las_ptr lbase = (las_ptr)tile;
    #pragma unroll
    for (int k = 0; k < 20; ++k) {
      const int chunk = k * TPB + tid;                // per-lane global chunk
      __builtin_amdgcn_global_load_lds((gas_ptr)(gtile + (size_t)chunk * 4),
                                       lbase + (size_t)(k * TPB) * 4, 16, 0, 0);
    }
    if (tid < 16) {   // remainder: chunks 1280..1295
      __builtin_amdgcn_global_load_lds((gas_ptr)(gtile + (size_t)(1280 + tid) * 4),
                                       lbase + (size_t)1280 * 4, 16, 0, 0);
    }
  }

  const float4 anc = ((const float4*)anchors)[a];   // coalesced, issued pre-barrier
  __syncthreads();   // 1-wave barrier: drains vmcnt (global_load_lds) + lgkm

  // ---- fused match_a: per-anchor IoU max / first-argmax over 24 GTs ----
  const float ax0 = anc.x - 0.5f * anc.z, ay0 = anc.y - 0.5f * anc.w;
  const float ax1 = anc.x + 0.5f * anc.z, ay1 = anc.y + 0.5f * anc.w;
  const float area_a = (ax1 - ax0) * (ay1 - ay0);
  float best_iou = -1.0f; int gi = 0;
  #pragma unroll 4
  for (int g = 0; g < NG_; ++g) {
    const float4 G = gt_xyxy[g];
    float lx = fmaxf(ax0, G.x), ly = fmaxf(ay0, G.y);
    float rx = fminf(ax1, G.z), ry = fminf(ay1, G.w);
    float ww = fmaxf(rx - lx, 0.f), hh = fmaxf(ry - ly, 0.f);
    float inter = ww * hh;
    float uni = area_a + gt_area[g] - inter;
    float iou = inter / fmaxf(uni, 1e-12f);
    if (iou > best_iou) { best_iou = iou; gi = g; }   // first-max tie-break
  }

  bool pos = (best_iou >= 0.5f);
  #pragma unroll
  for (int g = 0; g < NG_; ++g) pos = pos || (best_a_sh[g] == a);
  const bool ign = (best_iou > 0.4f) && !pos;
  const bool neg = !pos && !ign;
  const int tgt = pos ? label_sh[gi] : 0;

  // ---- single-pass logsumexp over own row (stride 81 dwords: 2-way, free) ----
  const float* row = &tile[tid * C_];
  float sum = 0.f;
  #pragma unroll 27
  for (int j = 0; j < C_; ++j) sum += __expf(row[j]);
  float ce = fmaxf(__logf(sum) - row[tgt], 0.f);

  neg_bits[idx] = neg ? __float_as_int(ce) : -1;   // sentinel -1 < all valid bits

  float pce = 0.f, reg = 0.f;
  if (pos) {
    pce = ce;
    const float4 bp = ((const float4*)box_pred)[idx];
    const float4 G  = gt_cc[gi];
    const float tx = (G.x - anc.x) / anc.z / 0.1f;
    const float ty = (G.y - anc.y) / anc.w / 0.1f;
    const float tw = logf(G.z / anc.z) / 0.2f;
    const float th = logf(G.w / anc.w) / 0.2f;
    float d, ad;
    d = bp.x - tx; ad = fabsf(d); reg += (ad < 1.f) ? 0.5f * d * d : (ad - 0.5f);
    d = bp.y - ty; ad = fabsf(d); reg += (ad < 1.f) ? 0.5f * d * d : (ad - 0.5f);
    d = bp.z - tw; ad = fabsf(d); reg += (ad < 1.f) ? 0.5f * d * d : (ad - 0.5f);
    d = bp.w - th; ad = fabsf(d); reg += (ad < 1.f) ? 0.5f * d * d : (ad - 0.5f);
  }

  // ---- wave reduction -> 4 atomics per block ----
  const int np_w = __popcll(__ballot(pos));
  const int nn_w = __popcll(__ballot(pos || ign));
  const float pce_w = wave_sum_f(pce);
  const float reg_w = wave_sum_f(reg);
  if (tid == 0) {
    if (np_w) atomicAdd(&num_pos_g[b], np_w);
    if (nn_w) atomicAdd(&notneg_g[b], nn_w);
    if (pce_w != 0.f) atomicAdd(&pos_ce_g[b], pce_w);
    if (reg_w != 0.f) atomicAdd(&reg_sum_g[b], reg_w);
  }
}

// ---------- K4: per-batch exact top-k sum via bitwise radix select + final ----------
__global__ __launch_bounds__(1024) void k_select(
    const int* __restrict__ neg_bits,
    const int* __restrict__ num_pos_g, const int* __restrict__ notneg_g,
    const float* __restrict__ pos_ce_g, const float* __restrict__ reg_sum_g,
    float* __restrict__ out)
{
  const int b = blockIdx.x;
  const int t = threadIdx.x;
  const int wave = t >> 6, lane = t & 63;
  __shared__ unsigned cnt_sh[32];            // one pre-zeroed counter per bit
  __shared__ float f1_sh[16], f0_sh[16];
  __shared__ unsigned cg_sh[16];
  if (t < 32) cnt_sh[t] = 0;
  int v[32];   // all 32768 values of this batch live in block registers
  const int4* src4 = (const int4*)(neg_bits + (size_t)b * NA_);
  #pragma unroll
  for (int i = 0; i < 8; ++i) *(int4*)&v[4 * i] = src4[t + (i << 10)];   // coalesced 16B/lane
  const int np = num_pos_g[b];
  const int negc = NA_ - notneg_g[b];
  const int k1 = min(3 * np, negc);
  const int k0 = min(100, negc);
  __syncthreads();   // cnt_sh zeroed before first atomic
  int T1 = 0, T0 = 0;   // ce>=0 -> bits monotone as signed int; sentinel -1 never counted
  for (int bit = 30; bit >= 0; --bit) {
    const int t1 = T1 | (1 << bit);
    const int t0 = T0 | (1 << bit);
    unsigned c = 0;
    #pragma unroll
    for (int i = 0; i < 32; ++i) {
      if (v[i] >= t1) c += (1u << 16);
      if (v[i] >= t0) c += 1u;
    }
    #pragma unroll
    for (int s = 32; s >= 1; s >>= 1) c += __shfl_xor(c, s);
    if (lane == 0) atomicAdd(&cnt_sh[bit], c);
    __syncthreads();                          // one barrier per bit
    const unsigned sum = cnt_sh[bit];
    if ((int)(sum >> 16) >= k1 && k1 > 0) T1 = t1;
    if ((int)(sum & 0xFFFFu) >= k0 && k0 > 0) T0 = t0;
  }
  float s1 = 0.f, s0 = 0.f; unsigned cg = 0;
  #pragma unroll
  for (int i = 0; i < 32; ++i) {
    const int x = v[i];
    if (x > T1) { s1 += __int_as_float(x); cg += (1u << 16); }
    if (x > T0) { s0 += __int_as_float(x); cg += 1u; }
  }
  #pragma unroll
  for (int s = 32; s >= 1; s >>= 1) {
    s1 += __shfl_xor(s1, s); s0 += __shfl_xor(s0, s); cg += __shfl_xor(cg, s);
  }
  if (lane == 0) { f1_sh[wave] = s1; f0_sh[wave] = s0; cg_sh[wave] = cg; }
  __syncthreads();
  if (t == 0) {
    float S1 = 0.f, S0 = 0.f; unsigned CG = 0;
    for (int w = 0; w < 16; ++w) { S1 += f1_sh[w]; S0 += f0_sh[w]; CG += cg_sh[w]; }
    const int cg1 = (int)(CG >> 16), cg0 = (int)(CG & 0xFFFFu);
    // sum of top-k == sum(v > v_k) + (k - count_gt) * v_k  (ties handled exactly)
    const float topk1 = (k1 > 0) ? (S1 + (float)(k1 - cg1) * __int_as_float(T1)) : 0.f;
    const float topk0 = (k0 > 0) ? (S0 + (float)(k0 - cg0) * __int_as_float(T0)) : 0.f;
    const float npf = (float)np;
    const float pce = pos_ce_g[b];
    float cls;
    if (np > 0)
      cls = (k1 > 0) ? (pce + topk1) / fmaxf(npf + (float)k1, 1.f)
                     : pce / fmaxf(npf, 1.f);
    else
      cls = (k0 > 0) ? topk0 / fmaxf((float)k0, 1.f) : 0.f;
    const float reg = (np > 0) ? reg_sum_g[b] / fmaxf(npf * 4.f, 1.f) : 0.f;
    // fused final reduction: out pre-zeroed by k_match_b block (0,0)
    atomicAdd(&out[0], cls * (1.0f / B_));
    atomicAdd(&out[1], reg * (1.0f / B_));
    atomicAdd(&out[2], npf * (1.0f / B_));   // exact: multiples of 1/32, sum < 2^11
  }
}

extern "C" void kernel_launch(void* const* d_in, const int* in_sizes, int n_in,
                              void* d_out, int out_size, void* d_ws, size_t ws_size,
                              hipStream_t stream) {
  const float* cls_pred  = (const float*)d_in[0];
  const float* box_pred  = (const float*)d_in[1];
  const float* anchors   = (const float*)d_in[2];
  const float* gt_boxes  = (const float*)d_in[3];
  const int*   gt_labels = (const int*)d_in[4];
  float* out = (float*)d_out;

  char* ws = (char*)d_ws;
  int*   best_anchor = (int*)ws;                                      // 32*24*4 B
  int*   num_pos_g = (int*)(ws + 6144);
  int*   notneg_g  = (int*)(ws + 6144 + 128);
  float* pos_ce_g  = (float*)(ws + 6144 + 256);
  float* reg_sum_g = (float*)(ws + 6144 + 384);
  int*   neg_bits  = (int*)(ws + 8192);                               // 4 MB

  hipLaunchKernelGGL(k_match_b, dim3(NG_, B_), dim3(256), 0, stream,
                     anchors, gt_boxes, best_anchor,
                     num_pos_g, notneg_g, pos_ce_g, reg_sum_g, out);
  hipLaunchKernelGGL(k_ce, dim3(NA_ / TPB, B_), dim3(TPB), 0, stream,
                     cls_pred, box_pred, anchors, gt_boxes, gt_labels,
                     best_anchor, neg_bits,
                     num_pos_g, notneg_g, pos_ce_g, reg_sum_g);
  hipLaunchKernelGGL(k_select, dim3(B_), dim3(1024), 0, stream,
                     neg_bits, num_pos_g, notneg_g, pos_ce_g, reg_sum_g, out);
}

// Round 2
// 609.417 us; speedup vs baseline: 1.0550x; 1.0550x over previous
//
#include <hip/hip_runtime.h>
#include <math.h>

#define B_  32
#define NA_ 32768
#define C_  81
#define NG_ 24

// ---------- helpers ----------
__device__ inline float wave_sum_f(float v) {
  #pragma unroll
  for (int s = 32; s >= 1; s >>= 1) v += __shfl_xor(v, s);
  return v;
}
__device__ inline int wave_sum_i(int v) {
  #pragma unroll
  for (int s = 32; s >= 1; s >>= 1) v += __shfl_xor(v, s);
  return v;
}
__device__ inline unsigned long long shflx_u64(unsigned long long v, int s) {
  int lo = __shfl_xor((int)(unsigned)(v & 0xFFFFFFFFULL), s);
  int hi = __shfl_xor((int)(unsigned)(v >> 32), s);
  return ((unsigned long long)(unsigned)hi << 32) | (unsigned)lo;
}

// ---------- K1b: one block per (gt, batch): full argmax over anchors ----------
// Also zeroes the accumulators + out (block (0,0)); plain store, no atomics.
__global__ __launch_bounds__(256) void k_match_b(
    const float* __restrict__ anchors, const float* __restrict__ gt_boxes,
    int* __restrict__ best_anchor,
    int* num_pos_g, int* notneg_g, float* pos_ce_g, float* reg_sum_g, float* out)
{
  const int g = blockIdx.x, b = blockIdx.y;
  const int tid = threadIdx.x, wave = tid >> 6, lane = tid & 63;
  if (g == 0 && b == 0) {
    if (tid < B_) { num_pos_g[tid] = 0; notneg_g[tid] = 0; pos_ce_g[tid] = 0.f; reg_sum_g[tid] = 0.f; }
    else if (tid < B_ + 3) out[tid - B_] = 0.f;
  }
  const float* gp = gt_boxes + ((size_t)b * NG_ + g) * 4;
  const float gx0 = gp[0] - 0.5f * gp[2], gy0 = gp[1] - 0.5f * gp[3];
  const float gx1 = gp[0] + 0.5f * gp[2], gy1 = gp[1] + 0.5f * gp[3];
  const float area_g = (gx1 - gx0) * (gy1 - gy0);
  unsigned long long key = 0ULL;   // (iou_bits<<32) | ~a  : max => first-max anchor
  #pragma unroll 4
  for (int i = 0; i < NA_ / 256; ++i) {
    const int a = i * 256 + tid;                 // increasing a per thread
    const float4 anc = ((const float4*)anchors)[a];
    const float ax0 = anc.x - 0.5f * anc.z, ay0 = anc.y - 0.5f * anc.w;
    const float ax1 = anc.x + 0.5f * anc.z, ay1 = anc.y + 0.5f * anc.w;
    float lx = fmaxf(ax0, gx0), ly = fmaxf(ay0, gy0);
    float rx = fminf(ax1, gx1), ry = fminf(ay1, gy1);
    float ww = fmaxf(rx - lx, 0.f), hh = fmaxf(ry - ly, 0.f);
    float inter = ww * hh;
    float uni = (ax1 - ax0) * (ay1 - ay0) + area_g - inter;
    float iou = inter / fmaxf(uni, 1e-12f);
    unsigned long long k2 =
        ((unsigned long long)__float_as_uint(iou) << 32) | (unsigned)(~(unsigned)a);
    if (k2 > key) key = k2;
  }
  #pragma unroll
  for (int s = 32; s >= 1; s >>= 1) {
    unsigned long long o = shflx_u64(key, s);
    if (o > key) key = o;
  }
  __shared__ unsigned long long red[4];
  if (lane == 0) red[wave] = key;
  __syncthreads();
  if (tid == 0) {
    unsigned long long k = red[0];
    for (int w = 1; w < 4; ++w) if (red[w] > k) k = red[w];
    best_anchor[b * NG_ + g] = (int)(~(unsigned)k);
  }
}

// ---------- K2: fused match_a + CE, streaming direct loads (no LDS tile) ----------
// Thread-per-row. Rows are 324 B (4B-aligned only), so each lane reads the 21
// 16B-aligned float4 windows covering its row and masks the <=3 edge elements
// (phase p = lane&3, loop-invariant since rows step by 64). Masked elems use
// exp(-1e30)=0: exact no-op. Deep ILP: 21 loads in flight per wave, 8 waves/CU,
// no barriers in the row loop -> latency-tolerant streaming at HBM rate.
#define RPT  8                     // rows per thread
#define TPB2 256                   // threads per block
// grid.x = NA_/(TPB2*RPT) = 16, grid.y = B_
__global__ __launch_bounds__(256, 2) void k_ce(
    const float* __restrict__ cls_pred, const float* __restrict__ box_pred,
    const float* __restrict__ anchors, const float* __restrict__ gt_boxes,
    const int* __restrict__ gt_labels, const int* __restrict__ best_anchor,
    int* __restrict__ neg_bits,
    int* __restrict__ num_pos_g, int* __restrict__ notneg_g,
    float* __restrict__ pos_ce_g, float* __restrict__ reg_sum_g)
{
  __shared__ float4 gt_xyxy[NG_];
  __shared__ float4 gt_cc[NG_];
  __shared__ float  gt_area[NG_];
  __shared__ int    label_sh[NG_];
  __shared__ int    best_a_sh[NG_];
  const int b = blockIdx.y;
  const int tid = threadIdx.x;
  const int wave = tid >> 6, lane = tid & 63;

  if (tid < NG_) {
    const float* g = gt_boxes + ((size_t)b * NG_ + tid) * 4;
    const float cx = g[0], cy = g[1], w = g[2], h = g[3];
    const float x0 = cx - 0.5f * w, y0 = cy - 0.5f * h;
    const float x1 = cx + 0.5f * w, y1 = cy + 0.5f * h;
    gt_xyxy[tid] = make_float4(x0, y0, x1, y1);
    gt_cc[tid]   = make_float4(cx, cy, w, h);
    gt_area[tid] = (x1 - x0) * (y1 - y0);
    label_sh[tid]  = gt_labels[b * NG_ + tid];
    best_a_sh[tid] = best_anchor[b * NG_ + tid];
  }
  __syncthreads();   // only barrier in the kernel

  const int p = lane & 3;          // row phase: (idx*81)%4 == row%4 == lane%4
  const int base = blockIdx.x * (TPB2 * RPT) + wave * (64 * RPT);

  int   npc = 0, nnc = 0;
  float pce = 0.f, regs = 0.f;

  #pragma unroll 1
  for (int it = 0; it < RPT; ++it) {
    const int a = base + it * 64 + lane;          // consecutive lanes -> 20.7KB span
    const size_t idx = (size_t)b * NA_ + a;

    // ---- IoU max / first-argmax over 24 LDS-resident GTs ----
    const float4 anc = ((const float4*)anchors)[a];
    const float ax0 = anc.x - 0.5f * anc.z, ay0 = anc.y - 0.5f * anc.w;
    const float ax1 = anc.x + 0.5f * anc.z, ay1 = anc.y + 0.5f * anc.w;
    const float area_a = (ax1 - ax0) * (ay1 - ay0);
    float best_iou = -1.0f; int gi = 0;
    #pragma unroll 4
    for (int g = 0; g < NG_; ++g) {
      const float4 G = gt_xyxy[g];
      float lx = fmaxf(ax0, G.x), ly = fmaxf(ay0, G.y);
      float rx = fminf(ax1, G.z), ry = fminf(ay1, G.w);
      float ww = fmaxf(rx - lx, 0.f), hh = fmaxf(ry - ly, 0.f);
      float inter = ww * hh;
      float uni = area_a + gt_area[g] - inter;
      float iou = inter / fmaxf(uni, 1e-12f);
      if (iou > best_iou) { best_iou = iou; gi = g; }   // first-max tie-break
    }
    bool pos = (best_iou >= 0.5f);
    #pragma unroll
    for (int g = 0; g < NG_; ++g) pos = pos || (best_a_sh[g] == a);
    const bool ign = (best_iou > 0.4f) && !pos;
    const bool neg = !pos && !ign;
    const int tgt = pos ? label_sh[gi] : 0;

    // ---- streaming logsumexp: 21 aligned float4 windows, edge-masked ----
    const size_t d0 = idx * 81;                    // dword index of row start
    const float4* w4 = (const float4*)(cls_pred + (d0 & ~(size_t)3));
    float s0 = 0.f, s1 = 0.f, s2 = 0.f, s3 = 0.f;
    #pragma unroll
    for (int k = 0; k < 21; ++k) {
      float4 v = w4[k];
      if (k == 0) {                 // discard first p elems (prev row's data)
        v.x = (p > 0) ? -1e30f : v.x;
        v.y = (p > 1) ? -1e30f : v.y;
        v.z = (p > 2) ? -1e30f : v.z;
      }
      if (k == 20) {                // keep only c <= p (81 valid total)
        v.y = (p < 1) ? -1e30f : v.y;
        v.z = (p < 2) ? -1e30f : v.z;
        v.w = (p < 3) ? -1e30f : v.w;
      }
      s0 += __expf(v.x); s1 += __expf(v.y);
      s2 += __expf(v.z); s3 += __expf(v.w);
    }
    const float sum = (s0 + s1) + (s2 + s3);
    const float tv = cls_pred[d0 + tgt];           // L1-hot (row just streamed)
    const float ce = fmaxf(__logf(sum) - tv, 0.f);

    neg_bits[idx] = neg ? __float_as_int(ce) : -1; // sentinel -1 < all valid bits

    npc += pos;
    nnc += (pos || ign);
    if (pos) {
      pce += ce;
      const float4 bp = ((const float4*)box_pred)[idx];
      const float4 G  = gt_cc[gi];
      const float tx = (G.x - anc.x) / anc.z / 0.1f;
      const float ty = (G.y - anc.y) / anc.w / 0.1f;
      const float tw = logf(G.z / anc.z) / 0.2f;
      const float th = logf(G.w / anc.w) / 0.2f;
      float d, ad;
      d = bp.x - tx; ad = fabsf(d); regs += (ad < 1.f) ? 0.5f * d * d : (ad - 0.5f);
      d = bp.y - ty; ad = fabsf(d); regs += (ad < 1.f) ? 0.5f * d * d : (ad - 0.5f);
      d = bp.z - tw; ad = fabsf(d); regs += (ad < 1.f) ? 0.5f * d * d : (ad - 0.5f);
      d = bp.w - th; ad = fabsf(d); regs += (ad < 1.f) ? 0.5f * d * d : (ad - 0.5f);
    }
  }

  // ---- one wave-reduction + 4 atomics per wave (amortized over 512 rows) ----
  const int   np_w  = wave_sum_i(npc);
  const int   nn_w  = wave_sum_i(nnc);
  const float pce_w = wave_sum_f(pce);
  const float reg_w = wave_sum_f(regs);
  if (lane == 0) {
    if (np_w) atomicAdd(&num_pos_g[b], np_w);
    if (nn_w) atomicAdd(&notneg_g[b], nn_w);
    if (pce_w != 0.f) atomicAdd(&pos_ce_g[b], pce_w);
    if (reg_w != 0.f) atomicAdd(&reg_sum_g[b], reg_w);
  }
}

// ---------- K4: per-batch exact top-k sum via bitwise radix select + final ----------
__global__ __launch_bounds__(1024) void k_select(
    const int* __restrict__ neg_bits,
    const int* __restrict__ num_pos_g, const int* __restrict__ notneg_g,
    const float* __restrict__ pos_ce_g, const float* __restrict__ reg_sum_g,
    float* __restrict__ out)
{
  const int b = blockIdx.x;
  const int t = threadIdx.x;
  const int wave = t >> 6, lane = t & 63;
  __shared__ unsigned cnt_sh[32];            // one pre-zeroed counter per bit
  __shared__ float f1_sh[16], f0_sh[16];
  __shared__ unsigned cg_sh[16];
  if (t < 32) cnt_sh[t] = 0;
  int v[32];   // all 32768 values of this batch live in block registers
  const int4* src4 = (const int4*)(neg_bits + (size_t)b * NA_);
  #pragma unroll
  for (int i = 0; i < 8; ++i) *(int4*)&v[4 * i] = src4[t + (i << 10)];   // coalesced 16B/lane
  const int np = num_pos_g[b];
  const int negc = NA_ - notneg_g[b];
  const int k1 = min(3 * np, negc);
  const int k0 = min(100, negc);
  __syncthreads();   // cnt_sh zeroed before first atomic
  int T1 = 0, T0 = 0;   // ce>=0 -> bits monotone as signed int; sentinel -1 never counted
  for (int bit = 30; bit >= 0; --bit) {
    const int t1 = T1 | (1 << bit);
    const int t0 = T0 | (1 << bit);
    unsigned c = 0;
    #pragma unroll
    for (int i = 0; i < 32; ++i) {
      if (v[i] >= t1) c += (1u << 16);
      if (v[i] >= t0) c += 1u;
    }
    #pragma unroll
    for (int s = 32; s >= 1; s >>= 1) c += __shfl_xor(c, s);
    if (lane == 0) atomicAdd(&cnt_sh[bit], c);
    __syncthreads();                          // one barrier per bit
    const unsigned sum = cnt_sh[bit];
    if ((int)(sum >> 16) >= k1 && k1 > 0) T1 = t1;
    if ((int)(sum & 0xFFFFu) >= k0 && k0 > 0) T0 = t0;
  }
  float s1 = 0.f, s0 = 0.f; unsigned cg = 0;
  #pragma unroll
  for (int i = 0; i < 32; ++i) {
    const int x = v[i];
    if (x > T1) { s1 += __int_as_float(x); cg += (1u << 16); }
    if (x > T0) { s0 += __int_as_float(x); cg += 1u; }
  }
  #pragma unroll
  for (int s = 32; s >= 1; s >>= 1) {
    s1 += __shfl_xor(s1, s); s0 += __shfl_xor(s0, s); cg += __shfl_xor(cg, s);
  }
  if (lane == 0) { f1_sh[wave] = s1; f0_sh[wave] = s0; cg_sh[wave] = cg; }
  __syncthreads();
  if (t == 0) {
    float S1 = 0.f, S0 = 0.f; unsigned CG = 0;
    for (int w = 0; w < 16; ++w) { S1 += f1_sh[w]; S0 += f0_sh[w]; CG += cg_sh[w]; }
    const int cg1 = (int)(CG >> 16), cg0 = (int)(CG & 0xFFFFu);
    // sum of top-k == sum(v > v_k) + (k - count_gt) * v_k  (ties handled exactly)
    const float topk1 = (k1 > 0) ? (S1 + (float)(k1 - cg1) * __int_as_float(T1)) : 0.f;
    const float topk0 = (k0 > 0) ? (S0 + (float)(k0 - cg0) * __int_as_float(T0)) : 0.f;
    const float npf = (float)np;
    const float pce = pos_ce_g[b];
    float cls;
    if (np > 0)
      cls = (k1 > 0) ? (pce + topk1) / fmaxf(npf + (float)k1, 1.f)
                     : pce / fmaxf(npf, 1.f);
    else
      cls = (k0 > 0) ? topk0 / fmaxf((float)k0, 1.f) : 0.f;
    const float reg = (np > 0) ? reg_sum_g[b] / fmaxf(npf * 4.f, 1.f) : 0.f;
    // fused final reduction: out pre-zeroed by k_match_b block (0,0)
    atomicAdd(&out[0], cls * (1.0f / B_));
    atomicAdd(&out[1], reg * (1.0f / B_));
    atomicAdd(&out[2], npf * (1.0f / B_));   // exact: multiples of 1/32, sum < 2^11
  }
}

extern "C" void kernel_launch(void* const* d_in, const int* in_sizes, int n_in,
                              void* d_out, int out_size, void* d_ws, size_t ws_size,
                              hipStream_t stream) {
  const float* cls_pred  = (const float*)d_in[0];
  const float* box_pred  = (const float*)d_in[1];
  const float* anchors   = (const float*)d_in[2];
  const float* gt_boxes  = (const float*)d_in[3];
  const int*   gt_labels = (const int*)d_in[4];
  float* out = (float*)d_out;

  char* ws = (char*)d_ws;
  int*   best_anchor = (int*)ws;                                      // 32*24*4 B
  int*   num_pos_g = (int*)(ws + 6144);
  int*   notneg_g  = (int*)(ws + 6144 + 128);
  float* pos_ce_g  = (float*)(ws + 6144 + 256);
  float* reg_sum_g = (float*)(ws + 6144 + 384);
  int*   neg_bits  = (int*)(ws + 8192);                               // 4 MB

  hipLaunchKernelGGL(k_match_b, dim3(NG_, B_), dim3(256), 0, stream,
                     anchors, gt_boxes, best_anchor,
                     num_pos_g, notneg_g, pos_ce_g, reg_sum_g, out);
  hipLaunchKernelGGL(k_ce, dim3(NA_ / (TPB2 * RPT), B_), dim3(TPB2), 0, stream,
                     cls_pred, box_pred, anchors, gt_boxes, gt_labels,
                     best_anchor, neg_bits,
                     num_pos_g, notneg_g, pos_ce_g, reg_sum_g);
  hipLaunchKernelGGL(k_select, dim3(B_), dim3(1024), 0, stream,
                     neg_bits, num_pos_g, notneg_g, pos_ce_g, reg_sum_g, out);
}

// Round 3
// 562.911 us; speedup vs baseline: 1.1421x; 1.0826x over previous
//
#include <hip/hip_runtime.h>
#include <math.h>

#define B_  32
#define NA_ 32768
#define C_  81
#define NG_ 24

typedef const __attribute__((address_space(1))) unsigned int* gas_ptr;
typedef __attribute__((address_space(3))) unsigned int* las_ptr;

// ---------- helpers ----------
__device__ inline float wave_sum_f(float v) {
  #pragma unroll
  for (int s = 32; s >= 1; s >>= 1) v += __shfl_xor(v, s);
  return v;
}
__device__ inline int wave_sum_i(int v) {
  #pragma unroll
  for (int s = 32; s >= 1; s >>= 1) v += __shfl_xor(v, s);
  return v;
}
__device__ inline unsigned long long shflx_u64(unsigned long long v, int s) {
  int lo = __shfl_xor((int)(unsigned)(v & 0xFFFFFFFFULL), s);
  int hi = __shfl_xor((int)(unsigned)(v >> 32), s);
  return ((unsigned long long)(unsigned)hi << 32) | (unsigned)lo;
}

// ---------- K1b: one block per (gt, batch): full argmax over anchors ----------
// Also zeroes the accumulators + out (block (0,0)); plain store, no atomics.
__global__ __launch_bounds__(256) void k_match_b(
    const float* __restrict__ anchors, const float* __restrict__ gt_boxes,
    int* __restrict__ best_anchor,
    int* num_pos_g, int* notneg_g, float* pos_ce_g, float* reg_sum_g, float* out)
{
  const int g = blockIdx.x, b = blockIdx.y;
  const int tid = threadIdx.x, wave = tid >> 6, lane = tid & 63;
  if (g == 0 && b == 0) {
    if (tid < B_) { num_pos_g[tid] = 0; notneg_g[tid] = 0; pos_ce_g[tid] = 0.f; reg_sum_g[tid] = 0.f; }
    else if (tid < B_ + 3) out[tid - B_] = 0.f;
  }
  const float* gp = gt_boxes + ((size_t)b * NG_ + g) * 4;
  const float gx0 = gp[0] - 0.5f * gp[2], gy0 = gp[1] - 0.5f * gp[3];
  const float gx1 = gp[0] + 0.5f * gp[2], gy1 = gp[1] + 0.5f * gp[3];
  const float area_g = (gx1 - gx0) * (gy1 - gy0);
  unsigned long long key = 0ULL;   // (iou_bits<<32) | ~a  : max => first-max anchor
  #pragma unroll 4
  for (int i = 0; i < NA_ / 256; ++i) {
    const int a = i * 256 + tid;                 // increasing a per thread
    const float4 anc = ((const float4*)anchors)[a];
    const float ax0 = anc.x - 0.5f * anc.z, ay0 = anc.y - 0.5f * anc.w;
    const float ax1 = anc.x + 0.5f * anc.z, ay1 = anc.y + 0.5f * anc.w;
    float lx = fmaxf(ax0, gx0), ly = fmaxf(ay0, gy0);
    float rx = fminf(ax1, gx1), ry = fminf(ay1, gy1);
    float ww = fmaxf(rx - lx, 0.f), hh = fmaxf(ry - ly, 0.f);
    float inter = ww * hh;
    float uni = (ax1 - ax0) * (ay1 - ay0) + area_g - inter;
    float iou = inter / fmaxf(uni, 1e-12f);
    unsigned long long k2 =
        ((unsigned long long)__float_as_uint(iou) << 32) | (unsigned)(~(unsigned)a);
    if (k2 > key) key = k2;
  }
  #pragma unroll
  for (int s = 32; s >= 1; s >>= 1) {
    unsigned long long o = shflx_u64(key, s);
    if (o > key) key = o;
  }
  __shared__ unsigned long long red[4];
  if (lane == 0) red[wave] = key;
  __syncthreads();
  if (tid == 0) {
    unsigned long long k = red[0];
    for (int w = 1; w < 4; ++w) if (red[w] > k) k = red[w];
    best_anchor[b * NG_ + g] = (int)(~(unsigned)k);
  }
}

// ---------- K2: fused match_a + CE, double-buffered DMA staging ----------
// 1-wave blocks, 64-row tiles (20736 B), 2 LDS buffers (41.5 KB) -> 3 blocks/CU.
// Pipeline (T3 minimum 2-phase): issue 21 global_load_lds for tile t+1, compute
// tile t from the other buffer, then s_waitcnt vmcnt(0) (nearly free: loads had
// the whole compute phase to fly), swap. No barriers in the loop (single wave).
// grid = (24, B_): block j of batch b handles tiles j, j+24, ... (512 tiles/batch).
#define NBLK 24
__device__ inline void stage_tile(const float* __restrict__ cls_pred,
                                  int b, int tile, las_ptr lbase, int tid)
{
  const unsigned int* gtile =
      (const unsigned int*)(cls_pred + ((size_t)b * NA_ + (size_t)tile * 64) * C_);
  #pragma unroll
  for (int k = 0; k < 20; ++k) {
    const int chunk = k * 64 + tid;                  // per-lane global 16B chunk
    __builtin_amdgcn_global_load_lds((gas_ptr)(gtile + (size_t)chunk * 4),
                                     lbase + (size_t)(k * 64) * 4, 16, 0, 0);
  }
  // tail 256 B: all 64 lanes, 4 B each (dwords 5120..5183)
  __builtin_amdgcn_global_load_lds((gas_ptr)(gtile + 5120 + tid),
                                   lbase + 5120, 4, 0, 0);
}

__global__ __launch_bounds__(64) void k_ce(
    const float* __restrict__ cls_pred, const float* __restrict__ box_pred,
    const float* __restrict__ anchors, const float* __restrict__ gt_boxes,
    const int* __restrict__ gt_labels, const int* __restrict__ best_anchor,
    int* __restrict__ neg_bits,
    int* __restrict__ num_pos_g, int* __restrict__ notneg_g,
    float* __restrict__ pos_ce_g, float* __restrict__ reg_sum_g)
{
  __shared__ float tile_sh[2][64 * C_];      // 2 x 20736 B
  __shared__ float4 gt_xyxy[NG_];
  __shared__ float4 gt_cc[NG_];
  __shared__ float  gt_area[NG_];
  __shared__ int    label_sh[NG_];
  __shared__ int    best_a_sh[NG_];
  const int b = blockIdx.y;
  const int j = blockIdx.x;
  const int lane = threadIdx.x;              // 64 threads = 1 wave

  if (lane < NG_) {
    const float* g = gt_boxes + ((size_t)b * NG_ + lane) * 4;
    const float cx = g[0], cy = g[1], w = g[2], h = g[3];
    const float x0 = cx - 0.5f * w, y0 = cy - 0.5f * h;
    const float x1 = cx + 0.5f * w, y1 = cy + 0.5f * h;
    gt_xyxy[lane] = make_float4(x0, y0, x1, y1);
    gt_cc[lane]   = make_float4(cx, cy, w, h);
    gt_area[lane] = (x1 - x0) * (y1 - y0);
    label_sh[lane]  = gt_labels[b * NG_ + lane];
    best_a_sh[lane] = best_anchor[b * NG_ + lane];
  }
  __syncthreads();

  const int p = lane & 3;          // row phase: (81*lane) % 4 == lane % 4
  const int wbase = (81 * lane) & ~3;        // 16B-aligned window base (dwords)

  int   npc = 0, nnc = 0;
  float pce = 0.f, regs = 0.f;

  // ---- prologue: stage first tile, drain ----
  int tj = j;
  stage_tile(cls_pred, b, tj, (las_ptr)tile_sh[0], lane);
  asm volatile("s_waitcnt vmcnt(0)" ::: "memory");
  __builtin_amdgcn_sched_barrier(0);
  int cur = 0;

  while (true) {
    const int tn = tj + NBLK;
    const bool more = (tn < NA_ / 64);
    if (more) stage_tile(cls_pred, b, tn, (las_ptr)tile_sh[cur ^ 1], lane);

    // ======== compute tile tj from buffer cur ========
    const int a = tj * 64 + lane;
    const size_t idx = (size_t)b * NA_ + a;

    // ---- IoU max / first-argmax over 24 LDS-resident GTs ----
    const float4 anc = ((const float4*)anchors)[a];
    const float ax0 = anc.x - 0.5f * anc.z, ay0 = anc.y - 0.5f * anc.w;
    const float ax1 = anc.x + 0.5f * anc.z, ay1 = anc.y + 0.5f * anc.w;
    const float area_a = (ax1 - ax0) * (ay1 - ay0);
    float best_iou = -1.0f; int gi = 0;
    #pragma unroll 4
    for (int g = 0; g < NG_; ++g) {
      const float4 G = gt_xyxy[g];
      float lx = fmaxf(ax0, G.x), ly = fmaxf(ay0, G.y);
      float rx = fminf(ax1, G.z), ry = fminf(ay1, G.w);
      float ww = fmaxf(rx - lx, 0.f), hh = fmaxf(ry - ly, 0.f);
      float inter = ww * hh;
      float uni = area_a + gt_area[g] - inter;
      float iou = inter / fmaxf(uni, 1e-12f);
      if (iou > best_iou) { best_iou = iou; gi = g; }   // first-max tie-break
    }
    bool pos = (best_iou >= 0.5f);
    #pragma unroll
    for (int g = 0; g < NG_; ++g) pos = pos || (best_a_sh[g] == a);
    const bool ign = (best_iou > 0.4f) && !pos;
    const bool neg = !pos && !ign;
    const int tgt = pos ? label_sh[gi] : 0;

    // ---- logsumexp over own row: 21 edge-masked LDS float4 windows ----
    const float4* w4 = (const float4*)&tile_sh[cur][wbase];
    float s0 = 0.f, s1 = 0.f, s2 = 0.f, s3 = 0.f;
    #pragma unroll
    for (int k = 0; k < 21; ++k) {
      float4 v = w4[k];
      if (k == 0) {                 // discard first p elems (prev row's data)
        v.x = (p > 0) ? -1e30f : v.x;
        v.y = (p > 1) ? -1e30f : v.y;
        v.z = (p > 2) ? -1e30f : v.z;
      }
      if (k == 20) {                // keep only j <= p (81 valid total)
        v.y = (p < 1) ? -1e30f : v.y;
        v.z = (p < 2) ? -1e30f : v.z;
        v.w = (p < 3) ? -1e30f : v.w;
      }
      s0 += __expf(v.x); s1 += __expf(v.y);
      s2 += __expf(v.z); s3 += __expf(v.w);
    }
    const float sum = (s0 + s1) + (s2 + s3);
    const float tv = tile_sh[cur][81 * lane + tgt];
    const float ce = fmaxf(__logf(sum) - tv, 0.f);

    neg_bits[idx] = neg ? __float_as_int(ce) : -1;   // sentinel -1 < all valid bits

    npc += pos;
    nnc += (pos || ign);
    if (pos) {
      pce += ce;
      const float4 bp = ((const float4*)box_pred)[idx];
      const float4 G  = gt_cc[gi];
      const float tx = (G.x - anc.x) / anc.z / 0.1f;
      const float ty = (G.y - anc.y) / anc.w / 0.1f;
      const float tw = logf(G.z / anc.z) / 0.2f;
      const float th = logf(G.w / anc.w) / 0.2f;
      float d, ad;
      d = bp.x - tx; ad = fabsf(d); regs += (ad < 1.f) ? 0.5f * d * d : (ad - 0.5f);
      d = bp.y - ty; ad = fabsf(d); regs += (ad < 1.f) ? 0.5f * d * d : (ad - 0.5f);
      d = bp.z - tw; ad = fabsf(d); regs += (ad < 1.f) ? 0.5f * d * d : (ad - 0.5f);
      d = bp.w - th; ad = fabsf(d); regs += (ad < 1.f) ? 0.5f * d * d : (ad - 0.5f);
    }
    // ======== end compute ========

    if (!more) break;
    asm volatile("s_waitcnt vmcnt(0)" ::: "memory");   // next-tile loads done
    __builtin_amdgcn_sched_barrier(0);
    tj = tn; cur ^= 1;
  }

  // ---- one wave-reduction + 4 atomics per block ----
  const int   np_w  = wave_sum_i(npc);
  const int   nn_w  = wave_sum_i(nnc);
  const float pce_w = wave_sum_f(pce);
  const float reg_w = wave_sum_f(regs);
  if (lane == 0) {
    if (np_w) atomicAdd(&num_pos_g[b], np_w);
    if (nn_w) atomicAdd(&notneg_g[b], nn_w);
    if (pce_w != 0.f) atomicAdd(&pos_ce_g[b], pce_w);
    if (reg_w != 0.f) atomicAdd(&reg_sum_g[b], reg_w);
  }
}

// ---------- K4: per-batch exact top-k sum via bitwise radix select + final ----------
__global__ __launch_bounds__(1024) void k_select(
    const int* __restrict__ neg_bits,
    const int* __restrict__ num_pos_g, const int* __restrict__ notneg_g,
    const float* __restrict__ pos_ce_g, const float* __restrict__ reg_sum_g,
    float* __restrict__ out)
{
  const int b = blockIdx.x;
  const int t = threadIdx.x;
  const int wave = t >> 6, lane = t & 63;
  __shared__ unsigned cnt_sh[32];            // one pre-zeroed counter per bit
  __shared__ float f1_sh[16], f0_sh[16];
  __shared__ unsigned cg_sh[16];
  if (t < 32) cnt_sh[t] = 0;
  int v[32];   // all 32768 values of this batch live in block registers
  const int4* src4 = (const int4*)(neg_bits + (size_t)b * NA_);
  #pragma unroll
  for (int i = 0; i < 8; ++i) *(int4*)&v[4 * i] = src4[t + (i << 10)];   // coalesced 16B/lane
  const int np = num_pos_g[b];
  const int negc = NA_ - notneg_g[b];
  const int k1 = min(3 * np, negc);
  const int k0 = min(100, negc);
  __syncthreads();   // cnt_sh zeroed before first atomic
  int T1 = 0, T0 = 0;   // ce>=0 -> bits monotone as signed int; sentinel -1 never counted
  for (int bit = 30; bit >= 0; --bit) {
    const int t1 = T1 | (1 << bit);
    const int t0 = T0 | (1 << bit);
    unsigned c = 0;
    #pragma unroll
    for (int i = 0; i < 32; ++i) {
      if (v[i] >= t1) c += (1u << 16);
      if (v[i] >= t0) c += 1u;
    }
    #pragma unroll
    for (int s = 32; s >= 1; s >>= 1) c += __shfl_xor(c, s);
    if (lane == 0) atomicAdd(&cnt_sh[bit], c);
    __syncthreads();                          // one barrier per bit
    const unsigned sum = cnt_sh[bit];
    if ((int)(sum >> 16) >= k1 && k1 > 0) T1 = t1;
    if ((int)(sum & 0xFFFFu) >= k0 && k0 > 0) T0 = t0;
  }
  float s1 = 0.f, s0 = 0.f; unsigned cg = 0;
  #pragma unroll
  for (int i = 0; i < 32; ++i) {
    const int x = v[i];
    if (x > T1) { s1 += __int_as_float(x); cg += (1u << 16); }
    if (x > T0) { s0 += __int_as_float(x); cg += 1u; }
  }
  #pragma unroll
  for (int s = 32; s >= 1; s >>= 1) {
    s1 += __shfl_xor(s1, s); s0 += __shfl_xor(s0, s); cg += __shfl_xor(cg, s);
  }
  if (lane == 0) { f1_sh[wave] = s1; f0_sh[wave] = s0; cg_sh[wave] = cg; }
  __syncthreads();
  if (t == 0) {
    float S1 = 0.f, S0 = 0.f; unsigned CG = 0;
    for (int w = 0; w < 16; ++w) { S1 += f1_sh[w]; S0 += f0_sh[w]; CG += cg_sh[w]; }
    const int cg1 = (int)(CG >> 16), cg0 = (int)(CG & 0xFFFFu);
    // sum of top-k == sum(v > v_k) + (k - count_gt) * v_k  (ties handled exactly)
    const float topk1 = (k1 > 0) ? (S1 + (float)(k1 - cg1) * __int_as_float(T1)) : 0.f;
    const float topk0 = (k0 > 0) ? (S0 + (float)(k0 - cg0) * __int_as_float(T0)) : 0.f;
    const float npf = (float)np;
    const float pce = pos_ce_g[b];
    float cls;
    if (np > 0)
      cls = (k1 > 0) ? (pce + topk1) / fmaxf(npf + (float)k1, 1.f)
                     : pce / fmaxf(npf, 1.f);
    else
      cls = (k0 > 0) ? topk0 / fmaxf((float)k0, 1.f) : 0.f;
    const float reg = (np > 0) ? reg_sum_g[b] / fmaxf(npf * 4.f, 1.f) : 0.f;
    // fused final reduction: out pre-zeroed by k_match_b block (0,0)
    atomicAdd(&out[0], cls * (1.0f / B_));
    atomicAdd(&out[1], reg * (1.0f / B_));
    atomicAdd(&out[2], npf * (1.0f / B_));   // exact: multiples of 1/32, sum < 2^11
  }
}

extern "C" void kernel_launch(void* const* d_in, const int* in_sizes, int n_in,
                              void* d_out, int out_size, void* d_ws, size_t ws_size,
                              hipStream_t stream) {
  const float* cls_pred  = (const float*)d_in[0];
  const float* box_pred  = (const float*)d_in[1];
  const float* anchors   = (const float*)d_in[2];
  const float* gt_boxes  = (const float*)d_in[3];
  const int*   gt_labels = (const int*)d_in[4];
  float* out = (float*)d_out;

  char* ws = (char*)d_ws;
  int*   best_anchor = (int*)ws;                                      // 32*24*4 B
  int*   num_pos_g = (int*)(ws + 6144);
  int*   notneg_g  = (int*)(ws + 6144 + 128);
  float* pos_ce_g  = (float*)(ws + 6144 + 256);
  float* reg_sum_g = (float*)(ws + 6144 + 384);
  int*   neg_bits  = (int*)(ws + 8192);                               // 4 MB

  hipLaunchKernelGGL(k_match_b, dim3(NG_, B_), dim3(256), 0, stream,
                     anchors, gt_boxes, best_anchor,
                     num_pos_g, notneg_g, pos_ce_g, reg_sum_g, out);
  hipLaunchKernelGGL(k_ce, dim3(NBLK, B_), dim3(64), 0, stream,
                     cls_pred, box_pred, anchors, gt_boxes, gt_labels,
                     best_anchor, neg_bits,
                     num_pos_g, notneg_g, pos_ce_g, reg_sum_g);
  hipLaunchKernelGGL(k_select, dim3(B_), dim3(1024), 0, stream,
                     neg_bits, num_pos_g, notneg_g, pos_ce_g, reg_sum_g, out);
}